// Round 8
// baseline (334.490 us; speedup 1.0000x reference)
//
#include <hip/hip_runtime.h>
#include <cstddef>

#define DEV static __device__ __forceinline__

typedef __attribute__((ext_vector_type(8))) short short8;
typedef __attribute__((ext_vector_type(4))) float floatx4;

DEV float siluf(float v) { return v / (1.f + expf(-v)); }

DEV unsigned short f2bf(float f) {             // RNE fp32 -> bf16
  unsigned int u = __float_as_uint(f);
  u += 0x7fff + ((u >> 16) & 1);
  return (unsigned short)(u >> 16);
}
DEV float bf2f(unsigned short u) {
  return __uint_as_float(((unsigned int)u) << 16);
}
DEV float4 bf2f4(ushort4 v) {
  return make_float4(bf2f(v.x), bf2f(v.y), bf2f(v.z), bf2f(v.w));
}

// quad_perm DPP add: CTRL=0xB1 swaps lane^1, CTRL=0x4E swaps lane^2 (within quad)
template <int CTRL>
DEV float qadd(float v) {
  int s = __builtin_amdgcn_update_dpp(__float_as_int(v), __float_as_int(v),
                                      CTRL, 0xF, 0xF, false);
  return v + __int_as_float(s);
}

DEV float softplusf(float s) {
  return fmaxf(s, 0.f) + log1pf(expf(-fabsf(s)));
}

// ---------------------------------------------------------------------------
// prep_k:
//  [0,3960)      weight fp32->bf16 (c2/c3 k-reordered: k = ij*256+c)
//  [3960,8056)   transpose-convert input_f -> inT bf16 (b,1024,512)
//  [8056,8184)   compose W1 = c1_w @ in_w[x-half] -> w_fz rows 0..255 (bf16)
//  [8184,8192)   bias1 = c1_w @ in_b[x] + c1_b -> bias_fz[0..255]; z-bias copy
//  [8192,8448)   z-half weight copy: w_fz rows 256..511 = bf16(in_w rows 256..511)
// ---------------------------------------------------------------------------
__global__ __launch_bounds__(256) void prep_k(
    const float* __restrict__ in_w, const float* __restrict__ c1_w,
    const float* __restrict__ c2_w, const float* __restrict__ c3_w,
    const float* __restrict__ out_w, const float* __restrict__ xw1,
    const float* __restrict__ xw2, const float* __restrict__ xw3,
    unsigned short* __restrict__ wsW,
    const float* __restrict__ input_f, unsigned short* __restrict__ inT,
    const float* __restrict__ in_b, const float* __restrict__ c1_b,
    unsigned short* __restrict__ w_fz, float* __restrict__ bias_fz)
{
  __shared__ float tile[32][33];
  __shared__ float c1s[1024];
  __shared__ float part[32][8];
  int bid = blockIdx.x;
  int t = threadIdx.x;
  if (bid < 3960) {
    int gid = bid * 256 + t;
    float v;
    if      (gid < 262144)  v = in_w[gid];
    else if (gid < 327680)  v = c1_w[gid - 262144];
    else if (gid < 589824)  {
      int off = gid - 327680;
      int o = off >> 10, kk = off & 1023, ij = kk >> 8, c = kk & 255;
      v = c2_w[o * 1024 + c * 4 + ij];
    }
    else if (gid < 851968)  {
      int off = gid - 589824;
      int o = off >> 10, kk = off & 1023, ij = kk >> 8, c = kk & 255;
      v = c3_w[o * 1024 + c * 4 + ij];
    }
    else if (gid < 983040)  v = out_w[gid - 851968];
    else if (gid < 993280)  v = xw1[gid - 983040];
    else if (gid < 1003520) v = xw2[gid - 993280];
    else                    v = xw3[gid - 1003520];
    wsW[gid] = f2bf(v);
  } else if (bid < 8056) {
    int idx = bid - 3960;              // < 4096
    int b = idx >> 9, blk = idx & 511;
    int pt = blk & 31, ct = blk >> 5;  // L=1024 -> 32 p-tiles; C=512 -> 16 c-tiles
    int p0 = pt * 32, c0 = ct * 32;
    int r = t >> 5, cc = t & 31;
#pragma unroll
    for (int i = 0; i < 4; i++) {
      int row = r + 8 * i;
      tile[row][cc] = input_f[((size_t)b * 512 + c0 + row) * 1024 + p0 + cc];
    }
    __syncthreads();
#pragma unroll
    for (int i = 0; i < 4; i++) {
      int row = r + 8 * i;
      inT[((size_t)b * 1024 + p0 + row) * 512 + c0 + cc] = f2bf(tile[cc][row]);
    }
  } else if (bid < 8184) {
    // W1 compose: 128 blocks, each = 4 o-rows x 256 ci-cols
    int ib = bid - 8056;
    int ot = ib >> 1;                     // 0..63 -> o base ot*4
    int ci = ((ib & 1) << 8) + t;         // 0..511
#pragma unroll
    for (int rr = 0; rr < 4; rr++)
      c1s[rr * 256 + t] = c1_w[(size_t)(ot * 4 + rr) * 256 + t];
    __syncthreads();
    float acc[4] = {0.f, 0.f, 0.f, 0.f};
#pragma unroll 4
    for (int m = 0; m < 256; m++) {
      float wv = in_w[(size_t)m * 512 + ci];
#pragma unroll
      for (int rr = 0; rr < 4; rr++) acc[rr] += c1s[rr * 256 + m] * wv;
    }
#pragma unroll
    for (int rr = 0; rr < 4; rr++)
      w_fz[(size_t)(ot * 4 + rr) * 512 + ci] = f2bf(acc[rr]);
  } else if (bid < 8192) {
    // bias1: 8 blocks x 32 o each
    int jb = bid - 8184;
    int oo = t >> 3, mc = t & 7;
    int o = jb * 32 + oo;
    float s = 0.f;
#pragma unroll 8
    for (int mm = 0; mm < 32; mm++) {
      int m = mc * 32 + mm;
      s += c1_w[(size_t)o * 256 + m] * in_b[m];
    }
    part[oo][mc] = s;
    __syncthreads();
    if (mc == 0) {
      float a = c1_b[o];
#pragma unroll
      for (int k = 0; k < 8; k++) a += part[oo][k];
      bias_fz[o] = a;
    }
    if (jb == 0) bias_fz[256 + t] = in_b[256 + t];
  } else {
    // z-half weight rows: 256 blocks
    int r = bid - 8192;
    const float* src = in_w + (size_t)(256 + r) * 512;
    w_fz[(size_t)(256 + r) * 512 + t]       = f2bf(src[t]);
    w_fz[(size_t)(256 + r) * 512 + 256 + t] = f2bf(src[256 + t]);
  }
}

// ---------------------------------------------------------------------------
// bf16 MFMA GEMM body: Y[m,n] = sum_k A[bb*sA+m*K+k] * B[bb*sB+n*K+k].
// 128x128 tile / 4 waves / 4x4 mfma_16x16x32_bf16. Double-buffered LDS, one
// barrier per K-step, next-tile loads issued before the MFMAs.
// EPI=0: O1 = fp32 Y0 (b,M,N), bias[m] (nullable).
// EPI=1: fused in-proj+c1 (M=1024 pix, N=512), bias[n]:
//        n<256  -> f1: O1=f1t bf16 [(b*1024+m)*256+n] + O2=f1b bf16 [(b*256+n)*1024+m]
//        n>=256 -> O3=szb bf16 silu [(b*1024+m)*256+(n-256)]
// ---------------------------------------------------------------------------
template <int EPI>
DEV void mgemm_body(const unsigned short* __restrict__ A, long long sA,
                    const unsigned short* __restrict__ B, long long sB,
                    const float* __restrict__ bias,
                    void* __restrict__ O1, void* __restrict__ O2,
                    void* __restrict__ O3,
                    int M, int N, int K, int Mt, int Nt, int bid)
{
  __shared__ __align__(16) unsigned short Ab[2 * 128 * 40];
  __shared__ __align__(16) unsigned short Bb[2 * 128 * 40];
  int tiles = Mt * Nt;
  int bb = bid / tiles;
  int rr = bid - bb * tiles;
  int m0 = (rr / Nt) * 128;
  int n0 = (rr % Nt) * 128;
  const unsigned short* Ap = A + (size_t)bb * sA;
  const unsigned short* Bp = B + (size_t)bb * sB;

  int t = threadIdx.x;
  int lane = t & 63;
  int wm = ((t >> 7) & 1) * 64;
  int wn = ((t >> 6) & 1) * 64;
  int l15 = lane & 15, quad = lane >> 4;

  int srow = t >> 1;
  int shalf = (t & 1) * 16;
  int arow = m0 + srow; if (arow > M - 1) arow = M - 1;
  int brow = n0 + srow; if (brow > N - 1) brow = N - 1;
  const unsigned short* ap = Ap + (size_t)arow * K + shalf;
  const unsigned short* bp = Bp + (size_t)brow * K + shalf;
  unsigned short* as = &Ab[srow * 40 + shalf];
  unsigned short* bs = &Bb[srow * 40 + shalf];

  floatx4 acc[4][4] = {};

  uint4 a0 = *(const uint4*)(ap);
  uint4 a1 = *(const uint4*)(ap + 8);
  uint4 b0 = *(const uint4*)(bp);
  uint4 b1 = *(const uint4*)(bp + 8);
  *(uint4*)as = a0; *(uint4*)(as + 8) = a1;
  *(uint4*)bs = b0; *(uint4*)(bs + 8) = b1;
  __syncthreads();
  int cur = 0;
  for (int k0 = 0; k0 < K; k0 += 32) {
    bool last = (k0 + 32 >= K);
    if (!last) {
      a0 = *(const uint4*)(ap + k0 + 32);
      a1 = *(const uint4*)(ap + k0 + 40);
      b0 = *(const uint4*)(bp + k0 + 32);
      b1 = *(const uint4*)(bp + k0 + 40);
    }
    int co = cur * 5120;
    short8 af[4], bfr[4];
#pragma unroll
    for (int i = 0; i < 4; i++)
      af[i] = *(const short8*)&Ab[co + (wm + i * 16 + l15) * 40 + quad * 8];
#pragma unroll
    for (int j = 0; j < 4; j++)
      bfr[j] = *(const short8*)&Bb[co + (wn + j * 16 + l15) * 40 + quad * 8];
#pragma unroll
    for (int i = 0; i < 4; i++)
#pragma unroll
      for (int j = 0; j < 4; j++)
        acc[i][j] = __builtin_amdgcn_mfma_f32_16x16x32_bf16(af[i], bfr[j],
                                                            acc[i][j], 0, 0, 0);
    if (!last) {
      int no = 5120 - co;
      *(uint4*)(as + no) = a0; *(uint4*)(as + no + 8) = a1;
      *(uint4*)(bs + no) = b0; *(uint4*)(bs + no + 8) = b1;
      __syncthreads();
      cur ^= 1;
    }
  }

  if (EPI == 1) {
    unsigned short* F1t = (unsigned short*)O1;
    unsigned short* F1b = (unsigned short*)O2;
    unsigned short* Sz  = (unsigned short*)O3;
    float bn[4]; int nn[4];
#pragma unroll
    for (int j = 0; j < 4; j++) { nn[j] = n0 + wn + j * 16 + l15; bn[j] = bias[nn[j]]; }
#pragma unroll
    for (int i = 0; i < 4; i++) {
      int pixb = m0 + wm + i * 16 + quad * 4;
#pragma unroll
      for (int j = 0; j < 4; j++) {
        int n = nn[j];
        float vr[4];
#pragma unroll
        for (int r = 0; r < 4; r++) vr[r] = acc[i][j][r] + bn[j];
        if (n < 256) {
#pragma unroll
          for (int r = 0; r < 4; r++)
            F1t[((size_t)bb * 1024 + pixb + r) * 256 + n] = f2bf(vr[r]);
          ushort4 o4;
          o4.x = f2bf(vr[0]); o4.y = f2bf(vr[1]); o4.z = f2bf(vr[2]); o4.w = f2bf(vr[3]);
          *(ushort4*)&F1b[((size_t)bb * 256 + n) * 1024 + pixb] = o4;
        } else {
#pragma unroll
          for (int r = 0; r < 4; r++)
            Sz[((size_t)bb * 1024 + pixb + r) * 256 + (n - 256)] =
                f2bf(siluf(vr[r]));
        }
      }
    }
  } else {
#pragma unroll
    for (int i = 0; i < 4; i++) {
      int m = m0 + wm + i * 16 + quad * 4;
#pragma unroll
      for (int j = 0; j < 4; j++) {
        int n = n0 + wn + j * 16 + l15;
        if (m < M && n < N) {
          float vr[4];
#pragma unroll
          for (int r = 0; r < 4; r++)
            vr[r] = acc[i][j][r] + (bias ? bias[m + r] : 0.f);
          float* Y0 = (float*)O1;
          float* yp = &Y0[((size_t)bb * M + m) * N + n];
#pragma unroll
          for (int r = 0; r < 4; r++) yp[(size_t)r * N] = vr[r];
        }
      }
    }
  }
}

template <int EPI>
__global__ __launch_bounds__(256) void mgemm_k(
    const unsigned short* __restrict__ A, long long sA,
    const unsigned short* __restrict__ B, long long sB,
    const float* __restrict__ bias, void* __restrict__ O1, void* __restrict__ O2,
    void* __restrict__ O3,
    int M, int N, int K, int Mt, int Nt)
{
  mgemm_body<EPI>(A, sA, B, sB, bias, O1, O2, O3, M, N, K, Mt, Nt, blockIdx.x);
}

// ---------------------------------------------------------------------------
// cgemm_k: small-tile GEMM for c2/c3 (64x32 tile, BK=64, dbuf LDS, 4 waves).
// Dual bf16 output, bias[m].
// ---------------------------------------------------------------------------
__global__ __launch_bounds__(256) void cgemm_k(
    const unsigned short* __restrict__ A,
    const unsigned short* __restrict__ B, long long sB,
    const float* __restrict__ bias,
    unsigned short* __restrict__ O1, unsigned short* __restrict__ O2,
    int M, int N, int K, int Mt, int Nt)
{
  __shared__ __align__(16) unsigned short Ab[2][64 * 72];
  __shared__ __align__(16) unsigned short Bb[2][32 * 72];
  int bid = blockIdx.x;
  int tiles = Mt * Nt;
  int bb = bid / tiles;
  int rr = bid - bb * tiles;
  int m0 = (rr / Nt) * 64;
  int n0 = (rr % Nt) * 32;
  const unsigned short* Bp = B + (size_t)bb * sB;

  int t = threadIdx.x, lane = t & 63;
  int wm = ((t >> 7) & 1) * 32;
  int wn = ((t >> 6) & 1) * 16;
  int l15 = lane & 15, quad = lane >> 4;

  int ar = t >> 2, ac = (t & 3) * 16;
  int brc = (t >> 2) & 31, bc = (t & 3) * 16;
  const unsigned short* apc = A + (size_t)(m0 + ar) * K + ac;
  const unsigned short* bpc = Bp + (size_t)(n0 + brc) * K + bc;

  floatx4 acc2[2] = {};

  uint4 av0 = *(const uint4*)(apc);
  uint4 av1 = *(const uint4*)(apc + 8);
  uint4 bv0 = {}, bv1 = {};
  if (t < 128) { bv0 = *(const uint4*)(bpc); bv1 = *(const uint4*)(bpc + 8); }
  {
    unsigned short* asc = &Ab[0][0] + ar * 72 + ac;
    *(uint4*)asc = av0; *(uint4*)(asc + 8) = av1;
    if (t < 128) {
      unsigned short* bsc = &Bb[0][0] + brc * 72 + bc;
      *(uint4*)bsc = bv0; *(uint4*)(bsc + 8) = bv1;
    }
  }
  __syncthreads();
  int cur = 0;
  for (int k0 = 0; k0 < K; k0 += 64) {
    bool last = (k0 + 64 >= K);
    if (!last) {
      av0 = *(const uint4*)(apc + k0 + 64);
      av1 = *(const uint4*)(apc + k0 + 72);
      if (t < 128) {
        bv0 = *(const uint4*)(bpc + k0 + 64);
        bv1 = *(const uint4*)(bpc + k0 + 72);
      }
    }
    const unsigned short* Ac = &Ab[cur][0];
    const unsigned short* Bc = &Bb[cur][0];
    short8 afc[2][2], bfc[2];
#pragma unroll
    for (int i = 0; i < 2; i++)
#pragma unroll
      for (int kk = 0; kk < 2; kk++)
        afc[i][kk] = *(const short8*)&Ac[(wm + i * 16 + l15) * 72 + kk * 32 + quad * 8];
#pragma unroll
    for (int kk = 0; kk < 2; kk++)
      bfc[kk] = *(const short8*)&Bc[(wn + l15) * 72 + kk * 32 + quad * 8];
#pragma unroll
    for (int kk = 0; kk < 2; kk++) {
      acc2[0] = __builtin_amdgcn_mfma_f32_16x16x32_bf16(afc[0][kk], bfc[kk], acc2[0], 0, 0, 0);
      acc2[1] = __builtin_amdgcn_mfma_f32_16x16x32_bf16(afc[1][kk], bfc[kk], acc2[1], 0, 0, 0);
    }
    if (!last) {
      unsigned short* asn = &Ab[cur ^ 1][0] + ar * 72 + ac;
      *(uint4*)asn = av0; *(uint4*)(asn + 8) = av1;
      if (t < 128) {
        unsigned short* bsn = &Bb[cur ^ 1][0] + brc * 72 + bc;
        *(uint4*)bsn = bv0; *(uint4*)(bsn + 8) = bv1;
      }
      __syncthreads();
      cur ^= 1;
    }
  }

#pragma unroll
  for (int i = 0; i < 2; i++) {
    int m = m0 + wm + i * 16 + quad * 4;
    int n = n0 + wn + l15;
    float vr[4];
#pragma unroll
    for (int r = 0; r < 4; r++) vr[r] = acc2[i][r] + bias[m + r];
#pragma unroll
    for (int r = 0; r < 4; r++)
      O1[((size_t)bb * M + m + r) * N + n] = f2bf(vr[r]);
    ushort4 o;
    o.x = f2bf(vr[0]); o.y = f2bf(vr[1]); o.z = f2bf(vr[2]); o.w = f2bf(vr[3]);
    *(ushort4*)&O2[((size_t)bb * N + n) * M + m] = o;
  }
}

// ---------------------------------------------------------------------------
// fat1: bid<64 -> xd12 GEMM (M=80,N=1024,K=256); else im2col2 from f1t.
// fat2: bid<16 -> xd2 GEMM (M=40,N=256,K=256); else im2col3 from f2t.
// ---------------------------------------------------------------------------
__global__ __launch_bounds__(256) void fat1_k(
    const unsigned short* __restrict__ w_xw12, const unsigned short* __restrict__ f1t,
    float* __restrict__ xd12, unsigned short* __restrict__ ic2)
{
  int bid = blockIdx.x;
  if (bid < 64) {
    mgemm_body<0>(w_xw12, 0, f1t, 1024 * 256, nullptr, xd12, nullptr, nullptr,
                  80, 1024, 256, 1, 8, bid);
  } else {
    int idx = (bid - 64) * 256 + threadIdx.x;   // 262144
    int cs = idx & 31, ij = (idx >> 5) & 3, n = (idx >> 7) & 255, b = idx >> 15;
    int i = ij >> 1, j = ij & 1;
    int y = n >> 4, x = n & 15;
    int pix = (2 * y + i) * 32 + 2 * x + j;
    uint4 v = *(const uint4*)&f1t[((size_t)b * 1024 + pix) * 256 + cs * 8];
    *(uint4*)&ic2[((size_t)b * 256 + n) * 1024 + ij * 256 + cs * 8] = v;
  }
}

__global__ __launch_bounds__(256) void fat2_k(
    const unsigned short* __restrict__ w_xw2, const unsigned short* __restrict__ f2t,
    float* __restrict__ xd2, unsigned short* __restrict__ ic3)
{
  int bid = blockIdx.x;
  if (bid < 16) {
    mgemm_body<0>(w_xw2, 0, f2t, 256 * 256, nullptr, xd2, nullptr, nullptr,
                  40, 256, 256, 1, 2, bid);
  } else {
    int idx = (bid - 16) * 256 + threadIdx.x;   // 65536
    int cs = idx & 31, ij = (idx >> 5) & 3, n = (idx >> 7) & 63, b = idx >> 13;
    int i = ij >> 1, j = ij & 1;
    int y = n >> 3, x = n & 7;
    int pix = (2 * y + i) * 16 + 2 * x + j;
    uint4 v = *(const uint4*)&f2t[((size_t)b * 256 + pix) * 256 + cs * 8];
    *(uint4*)&ic3[((size_t)b * 64 + n) * 1024 + ij * 256 + cs * 8] = v;
  }
}

// ---------------------------------------------------------------------------
// Segment-parallel selective scan, pass A. SEG=64. delta computed IN-KERNEL
// from dts (xd rows 0..7) + dtw/dtb (post_all deleted); B read directly from
// xd rows 8..23. lvl1 bid = sid*16+tseg (4096); lvl2 4096 + sid*4+tseg (1024).
// ---------------------------------------------------------------------------
#define SCAN_STEPA(DVV, XU, BVV) {                      \
    float e_ = __builtin_amdgcn_exp2f((DVV) * A2);      \
    h = h * e_ + (BVV) * ((DVV) * bf2f(XU));            \
    S += (DVV); }

__global__ __launch_bounds__(256) void scanA_k(
    const unsigned short* __restrict__ f1b, const unsigned short* __restrict__ f2b,
    const float* __restrict__ xd12, const float* __restrict__ xd2,
    const float* __restrict__ dtw1, const float* __restrict__ dtb1,
    const float* __restrict__ dtw2, const float* __restrict__ dtb2,
    const float* __restrict__ Al1, const float* __restrict__ Al2,
    float* __restrict__ cP, float* __restrict__ cQ)
{
  __shared__ __align__(16) float ld_dl[16][68];          // delta
  __shared__ __align__(16) float ld_ts[8][68];           // dts
  __shared__ __align__(16) float ld_b[16][68];           // B
  __shared__ __align__(16) unsigned short ld_x[16][72];  // x bf16
  int bid = blockIdx.x;
  int sid, tseg, L; const unsigned short* xin;
  if (bid < 4096) { sid = bid >> 4; tseg = bid & 15; L = 1024; xin = f1b; }
  else { int idx = bid - 4096; sid = idx >> 2; tseg = idx & 3; L = 256; xin = f2b; }
  int b = sid >> 5, dir = (sid >> 4) & 1, g = sid & 15;
  const float *xdp, *dtw, *dtbp, *Alp;
  if (bid < 4096) {
    xdp = xd12 + ((size_t)b * 80 + dir * 40) * 1024;
    if (dir == 0) { dtw = dtw1; dtbp = dtb1; Alp = Al1; }
    else          { dtw = dtw2; dtbp = dtb2; Alp = Al2; }
  } else {
    xdp = xd2 + (size_t)b * 40 * 256;
    dtw = dtw2; dtbp = dtb2; Alp = Al2;
  }
  int t = threadIdx.x, n = t & 15, dloc = t >> 4, d = g * 16 + dloc;
  int mbase = dir ? (L - 64 * (tseg + 1)) : 64 * tseg;

  {
    int r = t >> 4, cs = t & 15;
    *(float4*)&ld_b[r][cs * 4] =
        *(const float4*)(xdp + (size_t)(8 + r) * L + mbase + cs * 4);
    if (t < 128)
      *(float4*)&ld_ts[r][cs * 4] =
          *(const float4*)(xdp + (size_t)r * L + mbase + cs * 4);
    const unsigned short* xr = xin + ((size_t)b * 256 + g * 16 + r) * L + mbase;
    *(ushort4*)&ld_x[r][cs * 4] = *(const ushort4*)(xr + cs * 4);
  }
  __syncthreads();
  // delta: thread (dloc, n) fills cols 4n..4n+3 of row dloc
  {
    float w[8];
#pragma unroll
    for (int r = 0; r < 8; r++) w[r] = dtw[(size_t)d * 8 + r];
    float bb = dtbp[d];
#pragma unroll
    for (int k = 0; k < 4; k++) {
      int l = n * 4 + k;
      float s = bb;
#pragma unroll
      for (int r = 0; r < 8; r++) s += ld_ts[r][l] * w[r];
      ld_dl[dloc][l] = softplusf(s);
    }
  }
  __syncthreads();

  float A2 = -expf(Alp[d * 16 + n]) * 1.442695040888963f;
  float h = 0.f, S = 0.f;
  if (dir == 0) {
#pragma unroll
    for (int g4 = 0; g4 < 16; g4++) {
      int cb = 4 * g4;
      float4 dv4 = *(const float4*)&ld_dl[dloc][cb];
      ushort4 xu4 = *(const ushort4*)&ld_x[dloc][cb];
      float4 bv4 = *(const float4*)&ld_b[n][cb];
      SCAN_STEPA(dv4.x, xu4.x, bv4.x);
      SCAN_STEPA(dv4.y, xu4.y, bv4.y);
      SCAN_STEPA(dv4.z, xu4.z, bv4.z);
      SCAN_STEPA(dv4.w, xu4.w, bv4.w);
    }
  } else {
#pragma unroll
    for (int g4 = 0; g4 < 16; g4++) {
      int cb = 60 - 4 * g4;
      float4 dv4 = *(const float4*)&ld_dl[dloc][cb];
      ushort4 xu4 = *(const ushort4*)&ld_x[dloc][cb];
      float4 bv4 = *(const float4*)&ld_b[n][cb];
      SCAN_STEPA(dv4.w, xu4.w, bv4.w);
      SCAN_STEPA(dv4.z, xu4.z, bv4.z);
      SCAN_STEPA(dv4.y, xu4.y, bv4.y);
      SCAN_STEPA(dv4.x, xu4.x, bv4.x);
    }
  }
  cP[(size_t)bid * 256 + t] = __builtin_amdgcn_exp2f(S * A2);
  cQ[(size_t)bid * 256 + t] = h;
}

// ---------------------------------------------------------------------------
// scanB_k: per-chain serial combine of per-segment carries into EXCLUSIVE
// prefix initial states. Grid: 256 (lvl1, S=16) + 256 (lvl2, S=4) = 512.
// ---------------------------------------------------------------------------
__global__ __launch_bounds__(256) void scanB_k(
    const float* __restrict__ cP, const float* __restrict__ cQ,
    float* __restrict__ cH)
{
  int bid = blockIdx.x, t = threadIdx.x;
  if (bid < 256) {
    size_t base = (size_t)bid * 16 * 256 + t;
    float h = 0.f;
#pragma unroll
    for (int s = 0; s < 16; ++s) {
      size_t off = base + (size_t)s * 256;
      cH[off] = h;
      h = cP[off] * h + cQ[off];
    }
  } else {
    size_t base = (size_t)(4096 + (bid - 256) * 4) * 256 + t;
    float h = 0.f;
#pragma unroll
    for (int s = 0; s < 4; ++s) {
      size_t off = base + (size_t)s * 256;
      cH[off] = h;
      h = cP[off] * h + cQ[off];
    }
  }
}

// ---------------------------------------------------------------------------
// scanC (quad-n, SEG=64): lane owns 4 n-states of one d; block = 64 d x one
// 64-step segment. Initial h = ONE float4 from cH. delta computed in-kernel
// from dts + dtw/dtb into LDS table; B/C read from xd rows 8..23/24..39.
// Grid: lvl1 1024 + lvl2 256 + lvl3 64 = 1344.
// ---------------------------------------------------------------------------
#define QSTEP(DS, XU, CI, II) {                                         \
    float4 bv = *(const float4*)&ld_b[CI][n0];                          \
    float4 cv = *(const float4*)&ld_c[CI][n0];                          \
    float xs_ = bf2f(XU) * (DS);                                        \
    float4 e_;                                                          \
    e_.x = __builtin_amdgcn_exp2f((DS) * A4.x);                         \
    e_.y = __builtin_amdgcn_exp2f((DS) * A4.y);                         \
    e_.z = __builtin_amdgcn_exp2f((DS) * A4.z);                         \
    e_.w = __builtin_amdgcn_exp2f((DS) * A4.w);                         \
    h4.x = h4.x * e_.x + bv.x * xs_;                                    \
    h4.y = h4.y * e_.y + bv.y * xs_;                                    \
    h4.z = h4.z * e_.z + bv.z * xs_;                                    \
    h4.w = h4.w * e_.w + bv.w * xs_;                                    \
    float pp_ = h4.x * cv.x + h4.y * cv.y + h4.z * cv.z + h4.w * cv.w;  \
    pp_ = qadd<0xB1>(pp_);                                              \
    pp_ = qadd<0x4E>(pp_);                                              \
    ysel = (nq == (II)) ? pp_ : ysel; }

__global__ __launch_bounds__(256) void scanC_k(
    const unsigned short* __restrict__ f1b, const unsigned short* __restrict__ f2b,
    const unsigned short* __restrict__ f3b,
    const float* __restrict__ xd12, const float* __restrict__ xd2,
    const float* __restrict__ xd3,
    const float* __restrict__ dtw1, const float* __restrict__ dtb1,
    const float* __restrict__ dtw2, const float* __restrict__ dtb2,
    const float* __restrict__ dtw3, const float* __restrict__ dtb3,
    float* __restrict__ y1f, float* __restrict__ y1b,
    float* __restrict__ y2f, float* __restrict__ y2b,
    float* __restrict__ y3f, float* __restrict__ y3b,
    const float* __restrict__ Al1, const float* __restrict__ Dv1,
    const float* __restrict__ Al2, const float* __restrict__ Dv2,
    const float* __restrict__ Al3, const float* __restrict__ Dv3,
    const float* __restrict__ cH)
{
  __shared__ __align__(16) float ld_d[64][68];           // delta
  __shared__ __align__(16) float ld_ts[8][68];           // dts
  __shared__ __align__(16) unsigned short ld_xs[64][72]; // x bf16
  __shared__ __align__(16) float ld_b[64][20];           // B transposed [t][n]
  __shared__ __align__(16) float ld_c[64][20];           // C transposed [t][n]

  int bid = blockIdx.x;
  int b, dir, g4, tseg, L, lvl;
  const unsigned short* xin; const float *xdp, *dtw, *dtbp, *Alp, *Dvp; float* yo;
  if (bid < 1024) {
    b = bid >> 7; dir = (bid >> 6) & 1; g4 = (bid >> 4) & 3; tseg = bid & 15;
    L = 1024; xin = f1b; lvl = 1;
    xdp = xd12 + ((size_t)b * 80 + dir * 40) * 1024;
    if (dir == 0) { dtw = dtw1; dtbp = dtb1; Alp = Al1; Dvp = Dv1; yo = y1f; }
    else          { dtw = dtw2; dtbp = dtb2; Alp = Al2; Dvp = Dv2; yo = y1b; }
  } else if (bid < 1280) {
    int idx = bid - 1024;
    b = idx >> 5; dir = (idx >> 4) & 1; g4 = (idx >> 2) & 3; tseg = idx & 3;
    L = 256; xin = f2b; lvl = 2;
    xdp = xd2 + (size_t)b * 40 * 256;
    dtw = dtw2; dtbp = dtb2; Alp = Al2; Dvp = Dv2; yo = dir ? y2b : y2f;
  } else {
    int idx = bid - 1280;
    b = idx >> 3; dir = (idx >> 2) & 1; g4 = idx & 3; tseg = 0;
    L = 64; xin = f3b; lvl = 3;
    xdp = xd3 + (size_t)b * 40 * 64;
    dtw = dtw3; dtbp = dtb3; Alp = Al3; Dvp = Dv3; yo = dir ? y3b : y3f;
  }
  int mbase = dir ? (L - 64 * (tseg + 1)) : 64 * tseg;
  int t = threadIdx.x;
  int dl = t >> 2, nq = t & 3, n0 = nq * 4;
  int d = g4 * 64 + dl;

  // ---- initial h: one float4 from scanB's exclusive-prefix table ----
  float4 h4 = make_float4(0.f, 0.f, 0.f, 0.f);
  if (lvl != 3) {
    int gold = g4 * 4 + (dl >> 4);
    int soff = (lvl == 1) ? (b * 32 + dir * 16 + gold) * 16
                          : 4096 + (b * 32 + dir * 16 + gold) * 4;
    h4 = *(const float4*)&cH[(size_t)(soff + tseg) * 256 +
                             (size_t)((dl & 15) * 16 + n0)];
  }

  // ---- staging: x bf16 (rows = d), dts, B/C transposed to [t][n] ----
  {
    int rr = t >> 2, q = t & 3;
    const unsigned short* xr = xin + ((size_t)b * 256 + g4 * 64 + rr) * L + mbase;
#pragma unroll
    for (int j = 0; j < 4; ++j) {
      int c = q * 4 + 16 * j;
      *(ushort4*)&ld_xs[rr][c] = *(const ushort4*)(xr + c);
    }
    int nn = t >> 4, c4 = t & 15;
    const float* br = xdp + (size_t)(8 + nn) * L + mbase + c4 * 4;
    const float* cr = xdp + (size_t)(24 + nn) * L + mbase + c4 * 4;
    float4 bv = *(const float4*)br;
    float4 cv = *(const float4*)cr;
    ld_b[c4 * 4 + 0][nn] = bv.x; ld_b[c4 * 4 + 1][nn] = bv.y;
    ld_b[c4 * 4 + 2][nn] = bv.z; ld_b[c4 * 4 + 3][nn] = bv.w;
    ld_c[c4 * 4 + 0][nn] = cv.x; ld_c[c4 * 4 + 1][nn] = cv.y;
    ld_c[c4 * 4 + 2][nn] = cv.z; ld_c[c4 * 4 + 3][nn] = cv.w;
    if (t < 128)
      *(float4*)&ld_ts[t >> 4][c4 * 4] =
          *(const float4*)(xdp + (size_t)(t >> 4) * L + mbase + c4 * 4);
  }

  // A prescaled by log2(e) so e = exp2(delta * A4)
  float4 A4;
  A4.x = -expf(Alp[d * 16 + n0 + 0]) * 1.442695040888963f;
  A4.y = -expf(Alp[d * 16 + n0 + 1]) * 1.442695040888963f;
  A4.z = -expf(Alp[d * 16 + n0 + 2]) * 1.442695040888963f;
  A4.w = -expf(Alp[d * 16 + n0 + 3]) * 1.442695040888963f;
  float Dvv = Dvp[d];
  __syncthreads();

  // ---- delta: thread (dl, nq) fills cols 16nq..16nq+15 of row dl ----
  {
    float w[8];
#pragma unroll
    for (int r = 0; r < 8; r++) w[r] = dtw[(size_t)d * 8 + r];
    float bb = dtbp[d];
#pragma unroll
    for (int k = 0; k < 16; k++) {
      int l = nq * 16 + k;
      float s = bb;
#pragma unroll
      for (int r = 0; r < 8; r++) s += ld_ts[r][l] * w[r];
      ld_d[dl][l] = softplusf(s);
    }
  }
  __syncthreads();

  float* ybase = yo + ((size_t)b * L + mbase) * 256 + d;
  if (dir == 0) {
#pragma unroll 1
    for (int p = 0; p < 4; ++p) {
      float yk[4];
#pragma unroll
      for (int j = 0; j < 4; ++j) {
        int cb = 16 * p + 4 * j;
        float4 dv4 = *(const float4*)&ld_d[dl][cb];
        ushort4 xu4 = *(const ushort4*)&ld_xs[dl][cb];
        float ysel = 0.f;
        QSTEP(dv4.x, xu4.x, cb + 0, 0);
        QSTEP(dv4.y, xu4.y, cb + 1, 1);
        QSTEP(dv4.z, xu4.z, cb + 2, 2);
        QSTEP(dv4.w, xu4.w, cb + 3, 3);
        yk[j] = ysel;
      }
#pragma unroll
      for (int j = 0; j < 4; ++j) {
        int cst = 16 * p + 4 * j + nq;
        float xv = bf2f(ld_xs[dl][cst]);
        ybase[(size_t)cst * 256] = yk[j] + xv * Dvv;
      }
    }
  } else {
#pragma unroll 1
    for (int p = 0; p < 4; ++p) {
      float yk[4];
#pragma unroll
      for (int j = 0; j < 4; ++j) {
        int cb = 60 - 16 * p - 4 * j;
        float4 dv4 = *(const float4*)&ld_d[dl][cb];
        ushort4 xu4 = *(const ushort4*)&ld_xs[dl][cb];
        float ysel = 0.f;
        QSTEP(dv4.w, xu4.w, cb + 3, 0);
        QSTEP(dv4.z, xu4.z, cb + 2, 1);
        QSTEP(dv4.y, xu4.y, cb + 1, 2);
        QSTEP(dv4.x, xu4.x, cb + 0, 3);
        yk[j] = ysel;
      }
#pragma unroll
      for (int j = 0; j < 4; ++j) {
        int cst = 60 - 16 * p - 4 * j + (3 - nq);
        float xv = bf2f(ld_xs[dl][cst]);
        ybase[(size_t)cst * 256] = yk[j] + xv * Dvv;
      }
    }
  }
}

// ---------------------------------------------------------------------------
// LayerNorm(fwd)+LayerNorm(bwd) + optional upsample add + optional *silu(z).
// Wave-per-row: 4 rows/block, lane owns 4 channels, 6 shfl_xor reduce.
// ---------------------------------------------------------------------------
template <int OUTBF>
__global__ __launch_bounds__(256) void ln_combine(
    const float* __restrict__ yf, const float* __restrict__ yb,
    const float* __restrict__ gf, const float* __restrict__ bef,
    const float* __restrict__ gb, const float* __restrict__ beb,
    const float* __restrict__ up, int Wc,
    const unsigned short* __restrict__ szb, void* __restrict__ outv,
    int L, int Lsh, int Wfsh)
{
  int t = threadIdx.x;
  int row = blockIdx.x * 4 + (t >> 6);
  int lane = t & 63;
  int b = row >> Lsh, l = row & (L - 1);
  size_t base = (size_t)row * 256 + lane * 4;
  float4 vf = *(const float4*)&yf[base];
  float4 vb = *(const float4*)&yb[base];
  float4 s;
  s.x = vf.x + vf.y + vf.z + vf.w;
  s.y = vf.x * vf.x + vf.y * vf.y + vf.z * vf.z + vf.w * vf.w;
  s.z = vb.x + vb.y + vb.z + vb.w;
  s.w = vb.x * vb.x + vb.y * vb.y + vb.z * vb.z + vb.w * vb.w;
#pragma unroll
  for (int m = 1; m < 64; m <<= 1) {
    s.x += __shfl_xor(s.x, m);
    s.y += __shfl_xor(s.y, m);
    s.z += __shfl_xor(s.z, m);
    s.w += __shfl_xor(s.w, m);
  }
  const float inv = 1.f / 256.f;
  float muf = s.x * inv, varf = s.y * inv - muf * muf;
  float mub = s.z * inv, varb = s.w * inv - mub * mub;
  float rf = rsqrtf(varf + 1e-5f);
  float rb = rsqrtf(varb + 1e-5f);
  int dc = lane * 4;
  float4 gfv = *(const float4*)&gf[dc];
  float4 befv = *(const float4*)&bef[dc];
  float4 gbv = *(const float4*)&gb[dc];
  float4 bebv = *(const float4*)&beb[dc];
  float4 v;
  v.x = (vf.x - muf) * rf * gfv.x + befv.x + (vb.x - mub) * rb * gbv.x + bebv.x;
  v.y = (vf.y - muf) * rf * gfv.y + befv.y + (vb.y - mub) * rb * gbv.y + bebv.y;
  v.z = (vf.z - muf) * rf * gfv.z + befv.z + (vb.z - mub) * rb * gbv.z + bebv.z;
  v.w = (vf.w - muf) * rf * gfv.w + befv.w + (vb.w - mub) * rb * gbv.w + bebv.w;
  if (up) {
    int y = l >> Wfsh, x = l & ((1 << Wfsh) - 1);
    int lc = (y >> 1) * Wc + (x >> 1);
    float4 uv = *(const float4*)&up[((size_t)b * (L >> 2) + lc) * 256 + dc];
    v.x += uv.x; v.y += uv.y; v.z += uv.z; v.w += uv.w;
  }
  if (szb) {
    ushort4 su = *(const ushort4*)&szb[base];
    v.x *= bf2f(su.x); v.y *= bf2f(su.y); v.z *= bf2f(su.z); v.w *= bf2f(su.w);
  }
  if (OUTBF) {
    ushort4 o;
    o.x = f2bf(v.x); o.y = f2bf(v.y); o.z = f2bf(v.z); o.w = f2bf(v.w);
    *(ushort4*)&((unsigned short*)outv)[base] = o;
  } else {
    *(float4*)&((float*)outv)[base] = v;
  }
}

// ---------------------------------------------------------------------------
extern "C" void kernel_launch(void* const* d_in, const int* in_sizes, int n_in,
                              void* d_out, int out_size, void* d_ws, size_t ws_size,
                              hipStream_t stream) {
  (void)in_sizes; (void)n_in; (void)out_size; (void)ws_size;
  const float* input_f = (const float*)d_in[0];
  const float* in_w  = (const float*)d_in[1];
  const float* in_b  = (const float*)d_in[2];
  const float* c1_w  = (const float*)d_in[3];
  const float* c1_b  = (const float*)d_in[4];
  const float* c2_w  = (const float*)d_in[5];
  const float* c2_b  = (const float*)d_in[6];
  const float* c3_w  = (const float*)d_in[7];
  const float* c3_b  = (const float*)d_in[8];
  const float* out_w = (const float*)d_in[9];
  const float* out_b = (const float*)d_in[10];
  const float* xw1  = (const float*)d_in[11];
  const float* dtw1 = (const float*)d_in[12];
  const float* dtb1 = (const float*)d_in[13];
  const float* Al1  = (const float*)d_in[14];
  const float* Dv1  = (const float*)d_in[15];
  const float* g1   = (const float*)d_in[16];
  const float* be1  = (const float*)d_in[17];
  const float* xw2  = (const float*)d_in[18];
  const float* dtw2 = (const float*)d_in[19];
  const float* dtb2 = (const float*)d_in[20];
  const float* Al2  = (const float*)d_in[21];
  const float* Dv2  = (const float*)d_in[22];
  const float* g2   = (const float*)d_in[23];
  const float* be2  = (const float*)d_in[24];
  const float* xw3  = (const float*)d_in[25];
  const float* dtw3 = (const float*)d_in[26];
  const float* dtb3 = (const float*)d_in[27];
  const float* Al3  = (const float*)d_in[28];
  const float* Dv3  = (const float*)d_in[29];
  const float* g3   = (const float*)d_in[30];
  const float* be3  = (const float*)d_in[31];

  float* ws = (float*)d_ws;
  constexpr size_t M1 = 2097152;   // 8*256*1024 floats = 8 MB
  // Region map; lifetimes verified against launch order:
  // R0 now holds xd12/xd2/xd3 (fp32, alive from fat1/fat2/xd3 until scanC).
  float* xd12 = ws;                 // (b,80,1024) 2.6MB
  float* xd2  = ws + 655360;        // (b,40,256)
  float* xd3  = ws + 737280;        // (b,40,64)
  unsigned short* f1t = (unsigned short*)(ws + M1);     // R1 [0,4MB) dead after fat1
  float* y1f = ws + M1;                                 // R1 (after f1t dead)
  unsigned short* szb = (unsigned short*)(ws + 2 * M1); // R2 [0,4MB) alive->ln1
  unsigned short* f1b = (unsigned short*)(ws + 3 * M1); // R3 [0,4MB) alive->scanC
  unsigned short* G = (unsigned short*)(ws + 3 * M1) + 2097152; // R3 [4,8MB)
  float* y1b = ws + 4 * M1;                             // R4
  unsigned short* inT = (unsigned short*)(ws + 5 * M1); // R5 [0,8MB) dead after ip2
  unsigned short* ic2 = inT;                            // R5 [0,4MB)
  unsigned short* ic3 = inT + 2097152;                  // R5 [4,8MB)
  size_t o = 6 * M1;
  unsigned short* f2b = (unsigned short*)(ws + o); o += 524288;  // 1MB used
  unsigned short* f3b = (unsigned short*)(ws + o); o += 131072;
  float* y2f  = ws + o; o += 524288;
  float* y2b  = ws + o; o += 524288;
  float* y3f  = ws + o; o += 131072;
  float* y3b  = ws + o; o += 131072;
  float* y3c  = ws + o; o += 131072;
  float* y2c  = ws + o; o += 524288;
  float* cP   = ws + o; o += 1310720;   // 5120 blocks x 256
  float* cQ   = ws + o; o += 1310720;
  float* cH   = ws + o; o += 1310720;   // scanB exclusive-prefix states
  unsigned short* wsW = (unsigned short*)(ws + o); o += 506880;
  float* bias_fz = ws + o; o += 512;
  unsigned short* w_fz = (unsigned short*)(ws + o); o += 131072;  // 512x512 bf16
  // pixel-major bf16 f2/f3 alias cQ (dead before scanA writes cQ):
  unsigned short* f2t = (unsigned short*)cQ;            // (b,256,256)
  unsigned short* f3t = (unsigned short*)(cQ + 262144); // (b,64,256)
  // bf16 weight sub-pointers:
  unsigned short* w_c2   = wsW + 327680;   // k-reordered
  unsigned short* w_c3   = wsW + 589824;   // k-reordered
  unsigned short* w_out  = wsW + 851968;
  unsigned short* w_xw12 = wsW + 983040;   // [xw1;xw2] stacked (80x256)
  unsigned short* w_xw2  = wsW + 993280;
  unsigned short* w_xw3  = wsW + 1003520;

  dim3 blk(256);

  // 1. weights->bf16 + input transpose + W1/bias compose (fused)
  prep_k<<<dim3(8448), blk, 0, stream>>>(in_w, c1_w, c2_w, c3_w, out_w,
                                         xw1, xw2, xw3, wsW, input_f, inT,
                                         in_b, c1_b, w_fz, bias_fz);
  // 2. fused in-proj+c1: f1t + f1b + szb in one GEMM
  mgemm_k<1><<<dim3(256), blk, 0, stream>>>(inT, 1024 * 512, w_fz, 0, bias_fz,
                                            f1t, f1b, szb, 1024, 512, 512, 8, 4);
  // 3. fat1: xd12 GEMM + im2col2 (both read f1t only)
  fat1_k<<<dim3(1088), blk, 0, stream>>>(w_xw12, f1t, xd12, ic2);
  // 4. c2 small-tile (dual bf16): f2b + f2t  (256 blocks)
  cgemm_k<<<dim3(256), blk, 0, stream>>>(w_c2, ic2, 256 * 1024, c2_b,
                                         f2b, f2t, 256, 256, 1024, 4, 8);
  // 5. fat2: xd2 GEMM + im2col3 (both read f2t only)
  fat2_k<<<dim3(272), blk, 0, stream>>>(w_xw2, f2t, xd2, ic3);
  // 6. c3 small-tile (dual bf16): f3b + f3t  (64 blocks)
  cgemm_k<<<dim3(64), blk, 0, stream>>>(w_c3, ic3, 64 * 1024, c3_b,
                                        f3b, f3t, 256, 64, 1024, 4, 2);
  // 7. xd3
  mgemm_k<0><<<dim3(8), blk, 0, stream>>>(w_xw3, 0, f3t, 64 * 256, nullptr,
                                          xd3, nullptr, nullptr, 40, 64, 256, 1, 1);
  // 8-10. segment-parallel scan, SEG=64; delta/B/C taken directly from xd
  scanA_k<<<dim3(5120), blk, 0, stream>>>(f1b, f2b, xd12, xd2,
                                          dtw1, dtb1, dtw2, dtb2,
                                          Al1, Al2, cP, cQ);
  scanB_k<<<dim3(512), blk, 0, stream>>>(cP, cQ, cH);
  scanC_k<<<dim3(1344), blk, 0, stream>>>(f1b, f2b, f3b, xd12, xd2, xd3,
                                          dtw1, dtb1, dtw2, dtb2, dtw3, dtb3,
                                          y1f, y1b, y2f, y2b, y3f, y3b,
                                          Al1, Dv1, Al2, Dv2, Al3, Dv3, cH);
  // 11-13. LN + combine, wave-per-row (level 1 multiplies silu(z), writes bf16 G)
  ln_combine<0><<<dim3(128), blk, 0, stream>>>(y3f, y3b, g3, be3, g3, be3,
                                               nullptr, 0, nullptr, y3c, 64, 6, 3);
  ln_combine<0><<<dim3(512), blk, 0, stream>>>(y2f, y2b, g2, be2, g2, be2,
                                               y3c, 8, nullptr, y2c, 256, 8, 4);
  ln_combine<1><<<dim3(2048), blk, 0, stream>>>(y1f, y1b, g1, be1, g2, be2,
                                                y2c, 16, szb, G, 1024, 10, 5);
  // 14. out-proj -> d_out fp32 (b,512,1024)
  mgemm_k<0><<<dim3(256), blk, 0, stream>>>(w_out, 0, G, 1024 * 256, out_b,
                                            (float*)d_out, nullptr, nullptr,
                                            512, 1024, 256, 4, 8);
}

// Round 9
// 313.923 us; speedup vs baseline: 1.0655x; 1.0655x over previous
//
#include <hip/hip_runtime.h>
#include <cstddef>

#define DEV static __device__ __forceinline__

typedef __attribute__((ext_vector_type(8))) short short8;
typedef __attribute__((ext_vector_type(4))) float floatx4;

DEV float siluf(float v) { return v / (1.f + expf(-v)); }

DEV unsigned short f2bf(float f) {             // RNE fp32 -> bf16
  unsigned int u = __float_as_uint(f);
  u += 0x7fff + ((u >> 16) & 1);
  return (unsigned short)(u >> 16);
}
DEV float bf2f(unsigned short u) {
  return __uint_as_float(((unsigned int)u) << 16);
}
DEV float4 bf2f4(ushort4 v) {
  return make_float4(bf2f(v.x), bf2f(v.y), bf2f(v.z), bf2f(v.w));
}

// quad_perm DPP add: CTRL=0xB1 swaps lane^1, CTRL=0x4E swaps lane^2 (within quad)
template <int CTRL>
DEV float qadd(float v) {
  int s = __builtin_amdgcn_update_dpp(__float_as_int(v), __float_as_int(v),
                                      CTRL, 0xF, 0xF, false);
  return v + __int_as_float(s);
}

// ---------------------------------------------------------------------------
// prep_k:
//  [0,3960)      weight fp32->bf16 (c2/c3 k-reordered: k = ij*256+c)
//  [3960,8056)   transpose-convert input_f -> inT bf16 (b,1024,512)
//  [8056,8184)   compose W1 = c1_w @ in_w[x-half] -> w_fz rows 0..255 (bf16)
//  [8184,8192)   bias1 = c1_w @ in_b[x] + c1_b -> bias_fz[0..255]; z-bias copy
//  [8192,8448)   z-half weight copy: w_fz rows 256..511 = bf16(in_w rows 256..511)
// ---------------------------------------------------------------------------
__global__ __launch_bounds__(256) void prep_k(
    const float* __restrict__ in_w, const float* __restrict__ c1_w,
    const float* __restrict__ c2_w, const float* __restrict__ c3_w,
    const float* __restrict__ out_w, const float* __restrict__ xw1,
    const float* __restrict__ xw2, const float* __restrict__ xw3,
    unsigned short* __restrict__ wsW,
    const float* __restrict__ input_f, unsigned short* __restrict__ inT,
    const float* __restrict__ in_b, const float* __restrict__ c1_b,
    unsigned short* __restrict__ w_fz, float* __restrict__ bias_fz)
{
  __shared__ float tile[32][33];
  __shared__ float c1s[1024];
  __shared__ float part[32][8];
  int bid = blockIdx.x;
  int t = threadIdx.x;
  if (bid < 3960) {
    int gid = bid * 256 + t;
    float v;
    if      (gid < 262144)  v = in_w[gid];
    else if (gid < 327680)  v = c1_w[gid - 262144];
    else if (gid < 589824)  {
      int off = gid - 327680;
      int o = off >> 10, kk = off & 1023, ij = kk >> 8, c = kk & 255;
      v = c2_w[o * 1024 + c * 4 + ij];
    }
    else if (gid < 851968)  {
      int off = gid - 589824;
      int o = off >> 10, kk = off & 1023, ij = kk >> 8, c = kk & 255;
      v = c3_w[o * 1024 + c * 4 + ij];
    }
    else if (gid < 983040)  v = out_w[gid - 851968];
    else if (gid < 993280)  v = xw1[gid - 983040];
    else if (gid < 1003520) v = xw2[gid - 993280];
    else                    v = xw3[gid - 1003520];
    wsW[gid] = f2bf(v);
  } else if (bid < 8056) {
    int idx = bid - 3960;              // < 4096
    int b = idx >> 9, blk = idx & 511;
    int pt = blk & 31, ct = blk >> 5;  // L=1024 -> 32 p-tiles; C=512 -> 16 c-tiles
    int p0 = pt * 32, c0 = ct * 32;
    int r = t >> 5, cc = t & 31;
#pragma unroll
    for (int i = 0; i < 4; i++) {
      int row = r + 8 * i;
      tile[row][cc] = input_f[((size_t)b * 512 + c0 + row) * 1024 + p0 + cc];
    }
    __syncthreads();
#pragma unroll
    for (int i = 0; i < 4; i++) {
      int row = r + 8 * i;
      inT[((size_t)b * 1024 + p0 + row) * 512 + c0 + cc] = f2bf(tile[cc][row]);
    }
  } else if (bid < 8184) {
    // W1 compose: 128 blocks, each = 4 o-rows x 256 ci-cols
    int ib = bid - 8056;
    int ot = ib >> 1;                     // 0..63 -> o base ot*4
    int ci = ((ib & 1) << 8) + t;         // 0..511
#pragma unroll
    for (int rr = 0; rr < 4; rr++)
      c1s[rr * 256 + t] = c1_w[(size_t)(ot * 4 + rr) * 256 + t];
    __syncthreads();
    float acc[4] = {0.f, 0.f, 0.f, 0.f};
#pragma unroll 4
    for (int m = 0; m < 256; m++) {
      float wv = in_w[(size_t)m * 512 + ci];
#pragma unroll
      for (int rr = 0; rr < 4; rr++) acc[rr] += c1s[rr * 256 + m] * wv;
    }
#pragma unroll
    for (int rr = 0; rr < 4; rr++)
      w_fz[(size_t)(ot * 4 + rr) * 512 + ci] = f2bf(acc[rr]);
  } else if (bid < 8192) {
    // bias1: 8 blocks x 32 o each
    int jb = bid - 8184;
    int oo = t >> 3, mc = t & 7;
    int o = jb * 32 + oo;
    float s = 0.f;
#pragma unroll 8
    for (int mm = 0; mm < 32; mm++) {
      int m = mc * 32 + mm;
      s += c1_w[(size_t)o * 256 + m] * in_b[m];
    }
    part[oo][mc] = s;
    __syncthreads();
    if (mc == 0) {
      float a = c1_b[o];
#pragma unroll
      for (int k = 0; k < 8; k++) a += part[oo][k];
      bias_fz[o] = a;
    }
    if (jb == 0) bias_fz[256 + t] = in_b[256 + t];
  } else {
    // z-half weight rows: 256 blocks
    int r = bid - 8192;
    const float* src = in_w + (size_t)(256 + r) * 512;
    w_fz[(size_t)(256 + r) * 512 + t]       = f2bf(src[t]);
    w_fz[(size_t)(256 + r) * 512 + 256 + t] = f2bf(src[256 + t]);
  }
}

// ---------------------------------------------------------------------------
// bf16 MFMA GEMM body: Y[m,n] = sum_k A[bb*sA+m*K+k] * B[bb*sB+n*K+k].
// 128x128 tile / 4 waves / 4x4 mfma_16x16x32_bf16. Double-buffered LDS, one
// barrier per K-step, next-tile loads issued before the MFMAs.
// EPI=0: O1 = fp32 Y0 (b,M,N), bias[m] (nullable).
// EPI=1: fused in-proj+c1 (M=1024 pix, N=512), bias[n]:
//        n<256  -> f1: O1=f1t bf16 [(b*1024+m)*256+n] + O2=f1b bf16 [(b*256+n)*1024+m]
//        n>=256 -> O3=szb bf16 silu [(b*1024+m)*256+(n-256)]
// ---------------------------------------------------------------------------
template <int EPI>
DEV void mgemm_body(const unsigned short* __restrict__ A, long long sA,
                    const unsigned short* __restrict__ B, long long sB,
                    const float* __restrict__ bias,
                    void* __restrict__ O1, void* __restrict__ O2,
                    void* __restrict__ O3,
                    int M, int N, int K, int Mt, int Nt, int bid)
{
  __shared__ __align__(16) unsigned short Ab[2 * 128 * 40];
  __shared__ __align__(16) unsigned short Bb[2 * 128 * 40];
  int tiles = Mt * Nt;
  int bb = bid / tiles;
  int rr = bid - bb * tiles;
  int m0 = (rr / Nt) * 128;
  int n0 = (rr % Nt) * 128;
  const unsigned short* Ap = A + (size_t)bb * sA;
  const unsigned short* Bp = B + (size_t)bb * sB;

  int t = threadIdx.x;
  int lane = t & 63;
  int wm = ((t >> 7) & 1) * 64;
  int wn = ((t >> 6) & 1) * 64;
  int l15 = lane & 15, quad = lane >> 4;

  int srow = t >> 1;
  int shalf = (t & 1) * 16;
  int arow = m0 + srow; if (arow > M - 1) arow = M - 1;
  int brow = n0 + srow; if (brow > N - 1) brow = N - 1;
  const unsigned short* ap = Ap + (size_t)arow * K + shalf;
  const unsigned short* bp = Bp + (size_t)brow * K + shalf;
  unsigned short* as = &Ab[srow * 40 + shalf];
  unsigned short* bs = &Bb[srow * 40 + shalf];

  floatx4 acc[4][4] = {};

  uint4 a0 = *(const uint4*)(ap);
  uint4 a1 = *(const uint4*)(ap + 8);
  uint4 b0 = *(const uint4*)(bp);
  uint4 b1 = *(const uint4*)(bp + 8);
  *(uint4*)as = a0; *(uint4*)(as + 8) = a1;
  *(uint4*)bs = b0; *(uint4*)(bs + 8) = b1;
  __syncthreads();
  int cur = 0;
  for (int k0 = 0; k0 < K; k0 += 32) {
    bool last = (k0 + 32 >= K);
    if (!last) {
      a0 = *(const uint4*)(ap + k0 + 32);
      a1 = *(const uint4*)(ap + k0 + 40);
      b0 = *(const uint4*)(bp + k0 + 32);
      b1 = *(const uint4*)(bp + k0 + 40);
    }
    int co = cur * 5120;
    short8 af[4], bfr[4];
#pragma unroll
    for (int i = 0; i < 4; i++)
      af[i] = *(const short8*)&Ab[co + (wm + i * 16 + l15) * 40 + quad * 8];
#pragma unroll
    for (int j = 0; j < 4; j++)
      bfr[j] = *(const short8*)&Bb[co + (wn + j * 16 + l15) * 40 + quad * 8];
#pragma unroll
    for (int i = 0; i < 4; i++)
#pragma unroll
      for (int j = 0; j < 4; j++)
        acc[i][j] = __builtin_amdgcn_mfma_f32_16x16x32_bf16(af[i], bfr[j],
                                                            acc[i][j], 0, 0, 0);
    if (!last) {
      int no = 5120 - co;
      *(uint4*)(as + no) = a0; *(uint4*)(as + no + 8) = a1;
      *(uint4*)(bs + no) = b0; *(uint4*)(bs + no + 8) = b1;
      __syncthreads();
      cur ^= 1;
    }
  }

  if (EPI == 1) {
    unsigned short* F1t = (unsigned short*)O1;
    unsigned short* F1b = (unsigned short*)O2;
    unsigned short* Sz  = (unsigned short*)O3;
    float bn[4]; int nn[4];
#pragma unroll
    for (int j = 0; j < 4; j++) { nn[j] = n0 + wn + j * 16 + l15; bn[j] = bias[nn[j]]; }
#pragma unroll
    for (int i = 0; i < 4; i++) {
      int pixb = m0 + wm + i * 16 + quad * 4;
#pragma unroll
      for (int j = 0; j < 4; j++) {
        int n = nn[j];
        float vr[4];
#pragma unroll
        for (int r = 0; r < 4; r++) vr[r] = acc[i][j][r] + bn[j];
        if (n < 256) {
#pragma unroll
          for (int r = 0; r < 4; r++)
            F1t[((size_t)bb * 1024 + pixb + r) * 256 + n] = f2bf(vr[r]);
          ushort4 o4;
          o4.x = f2bf(vr[0]); o4.y = f2bf(vr[1]); o4.z = f2bf(vr[2]); o4.w = f2bf(vr[3]);
          *(ushort4*)&F1b[((size_t)bb * 256 + n) * 1024 + pixb] = o4;
        } else {
#pragma unroll
          for (int r = 0; r < 4; r++)
            Sz[((size_t)bb * 1024 + pixb + r) * 256 + (n - 256)] =
                f2bf(siluf(vr[r]));
        }
      }
    }
  } else {
#pragma unroll
    for (int i = 0; i < 4; i++) {
      int m = m0 + wm + i * 16 + quad * 4;
#pragma unroll
      for (int j = 0; j < 4; j++) {
        int n = n0 + wn + j * 16 + l15;
        if (m < M && n < N) {
          float vr[4];
#pragma unroll
          for (int r = 0; r < 4; r++)
            vr[r] = acc[i][j][r] + (bias ? bias[m + r] : 0.f);
          float* Y0 = (float*)O1;
          float* yp = &Y0[((size_t)bb * M + m) * N + n];
#pragma unroll
          for (int r = 0; r < 4; r++) yp[(size_t)r * N] = vr[r];
        }
      }
    }
  }
}

template <int EPI>
__global__ __launch_bounds__(256) void mgemm_k(
    const unsigned short* __restrict__ A, long long sA,
    const unsigned short* __restrict__ B, long long sB,
    const float* __restrict__ bias, void* __restrict__ O1, void* __restrict__ O2,
    void* __restrict__ O3,
    int M, int N, int K, int Mt, int Nt)
{
  mgemm_body<EPI>(A, sA, B, sB, bias, O1, O2, O3, M, N, K, Mt, Nt, blockIdx.x);
}

// ---------------------------------------------------------------------------
// cgemm_k: small-tile GEMM for c2/c3 (64x32 tile, BK=64, dbuf LDS, 4 waves).
// Dual bf16 output, bias[m].
// ---------------------------------------------------------------------------
__global__ __launch_bounds__(256) void cgemm_k(
    const unsigned short* __restrict__ A,
    const unsigned short* __restrict__ B, long long sB,
    const float* __restrict__ bias,
    unsigned short* __restrict__ O1, unsigned short* __restrict__ O2,
    int M, int N, int K, int Mt, int Nt)
{
  __shared__ __align__(16) unsigned short Ab[2][64 * 72];
  __shared__ __align__(16) unsigned short Bb[2][32 * 72];
  int bid = blockIdx.x;
  int tiles = Mt * Nt;
  int bb = bid / tiles;
  int rr = bid - bb * tiles;
  int m0 = (rr / Nt) * 64;
  int n0 = (rr % Nt) * 32;
  const unsigned short* Bp = B + (size_t)bb * sB;

  int t = threadIdx.x, lane = t & 63;
  int wm = ((t >> 7) & 1) * 32;
  int wn = ((t >> 6) & 1) * 16;
  int l15 = lane & 15, quad = lane >> 4;

  int ar = t >> 2, ac = (t & 3) * 16;
  int brc = (t >> 2) & 31, bc = (t & 3) * 16;
  const unsigned short* apc = A + (size_t)(m0 + ar) * K + ac;
  const unsigned short* bpc = Bp + (size_t)(n0 + brc) * K + bc;

  floatx4 acc2[2] = {};

  uint4 av0 = *(const uint4*)(apc);
  uint4 av1 = *(const uint4*)(apc + 8);
  uint4 bv0 = {}, bv1 = {};
  if (t < 128) { bv0 = *(const uint4*)(bpc); bv1 = *(const uint4*)(bpc + 8); }
  {
    unsigned short* asc = &Ab[0][0] + ar * 72 + ac;
    *(uint4*)asc = av0; *(uint4*)(asc + 8) = av1;
    if (t < 128) {
      unsigned short* bsc = &Bb[0][0] + brc * 72 + bc;
      *(uint4*)bsc = bv0; *(uint4*)(bsc + 8) = bv1;
    }
  }
  __syncthreads();
  int cur = 0;
  for (int k0 = 0; k0 < K; k0 += 64) {
    bool last = (k0 + 64 >= K);
    if (!last) {
      av0 = *(const uint4*)(apc + k0 + 64);
      av1 = *(const uint4*)(apc + k0 + 72);
      if (t < 128) {
        bv0 = *(const uint4*)(bpc + k0 + 64);
        bv1 = *(const uint4*)(bpc + k0 + 72);
      }
    }
    const unsigned short* Ac = &Ab[cur][0];
    const unsigned short* Bc = &Bb[cur][0];
    short8 afc[2][2], bfc[2];
#pragma unroll
    for (int i = 0; i < 2; i++)
#pragma unroll
      for (int kk = 0; kk < 2; kk++)
        afc[i][kk] = *(const short8*)&Ac[(wm + i * 16 + l15) * 72 + kk * 32 + quad * 8];
#pragma unroll
    for (int kk = 0; kk < 2; kk++)
      bfc[kk] = *(const short8*)&Bc[(wn + l15) * 72 + kk * 32 + quad * 8];
#pragma unroll
    for (int kk = 0; kk < 2; kk++) {
      acc2[0] = __builtin_amdgcn_mfma_f32_16x16x32_bf16(afc[0][kk], bfc[kk], acc2[0], 0, 0, 0);
      acc2[1] = __builtin_amdgcn_mfma_f32_16x16x32_bf16(afc[1][kk], bfc[kk], acc2[1], 0, 0, 0);
    }
    if (!last) {
      unsigned short* asn = &Ab[cur ^ 1][0] + ar * 72 + ac;
      *(uint4*)asn = av0; *(uint4*)(asn + 8) = av1;
      if (t < 128) {
        unsigned short* bsn = &Bb[cur ^ 1][0] + brc * 72 + bc;
        *(uint4*)bsn = bv0; *(uint4*)(bsn + 8) = bv1;
      }
      __syncthreads();
      cur ^= 1;
    }
  }

#pragma unroll
  for (int i = 0; i < 2; i++) {
    int m = m0 + wm + i * 16 + quad * 4;
    int n = n0 + wn + l15;
    float vr[4];
#pragma unroll
    for (int r = 0; r < 4; r++) vr[r] = acc2[i][r] + bias[m + r];
#pragma unroll
    for (int r = 0; r < 4; r++)
      O1[((size_t)bb * M + m + r) * N + n] = f2bf(vr[r]);
    ushort4 o;
    o.x = f2bf(vr[0]); o.y = f2bf(vr[1]); o.z = f2bf(vr[2]); o.w = f2bf(vr[3]);
    *(ushort4*)&O2[((size_t)bb * N + n) * M + m] = o;
  }
}

// ---------------------------------------------------------------------------
// fat1: bid<64 -> xd12 GEMM (M=80,N=1024,K=256); else im2col2 from f1t.
// fat2: bid<16 -> xd2 GEMM (M=40,N=256,K=256); else im2col3 from f2t.
// ---------------------------------------------------------------------------
__global__ __launch_bounds__(256) void fat1_k(
    const unsigned short* __restrict__ w_xw12, const unsigned short* __restrict__ f1t,
    float* __restrict__ xd12, unsigned short* __restrict__ ic2)
{
  int bid = blockIdx.x;
  if (bid < 64) {
    mgemm_body<0>(w_xw12, 0, f1t, 1024 * 256, nullptr, xd12, nullptr, nullptr,
                  80, 1024, 256, 1, 8, bid);
  } else {
    int idx = (bid - 64) * 256 + threadIdx.x;   // 262144
    int cs = idx & 31, ij = (idx >> 5) & 3, n = (idx >> 7) & 255, b = idx >> 15;
    int i = ij >> 1, j = ij & 1;
    int y = n >> 4, x = n & 15;
    int pix = (2 * y + i) * 32 + 2 * x + j;
    uint4 v = *(const uint4*)&f1t[((size_t)b * 1024 + pix) * 256 + cs * 8];
    *(uint4*)&ic2[((size_t)b * 256 + n) * 1024 + ij * 256 + cs * 8] = v;
  }
}

__global__ __launch_bounds__(256) void fat2_k(
    const unsigned short* __restrict__ w_xw2, const unsigned short* __restrict__ f2t,
    float* __restrict__ xd2, unsigned short* __restrict__ ic3)
{
  int bid = blockIdx.x;
  if (bid < 16) {
    mgemm_body<0>(w_xw2, 0, f2t, 256 * 256, nullptr, xd2, nullptr, nullptr,
                  40, 256, 256, 1, 2, bid);
  } else {
    int idx = (bid - 16) * 256 + threadIdx.x;   // 65536
    int cs = idx & 31, ij = (idx >> 5) & 3, n = (idx >> 7) & 63, b = idx >> 13;
    int i = ij >> 1, j = ij & 1;
    int y = n >> 3, x = n & 7;
    int pix = (2 * y + i) * 16 + 2 * x + j;
    uint4 v = *(const uint4*)&f2t[((size_t)b * 256 + pix) * 256 + cs * 8];
    *(uint4*)&ic3[((size_t)b * 64 + n) * 1024 + ij * 256 + cs * 8] = v;
  }
}

// ---------------------------------------------------------------------------
// post_all_k: delta = softplus(dts . dtw + dtb) for all 4 param-sets.
// (bc copy deleted: scans read B/C directly from xd rows 8..23 / 24..39.)
// ---------------------------------------------------------------------------
__global__ __launch_bounds__(256) void post_all_k(
    const float* __restrict__ xd12, const float* __restrict__ xd2,
    const float* __restrict__ xd3,
    const float* __restrict__ dtw1, const float* __restrict__ dtb1,
    const float* __restrict__ dtw2, const float* __restrict__ dtb2,
    const float* __restrict__ dtw3, const float* __restrict__ dtb3,
    float* __restrict__ d1f, float* __restrict__ d1b,
    float* __restrict__ d2g, float* __restrict__ d3g)
{
  int bid = blockIdx.x;
  const float* xd; int bstride, L; const float *dtw, *dtb; float *dg;
  int lt, b;
  if (bid < 512) {
    int r = bid; lt = r & 63; b = r >> 6;
    xd = xd12; bstride = 80 * 1024; L = 1024; dtw = dtw1; dtb = dtb1; dg = d1f;
  } else if (bid < 1024) {
    int r = bid - 512; lt = r & 63; b = r >> 6;
    xd = xd12 + 40 * 1024; bstride = 80 * 1024; L = 1024; dtw = dtw2; dtb = dtb2; dg = d1b;
  } else if (bid < 1152) {
    int r = bid - 1024; lt = r & 15; b = r >> 4;
    xd = xd2; bstride = 40 * 256; L = 256; dtw = dtw2; dtb = dtb2; dg = d2g;
  } else {
    int r = bid - 1152; lt = r & 3; b = r >> 2;
    xd = xd3; bstride = 40 * 64; L = 64; dtw = dtw3; dtb = dtb3; dg = d3g;
  }
  int l0 = lt * 16;
  __shared__ float dl[8][16];
  int t = threadIdx.x;
  const float* xb = xd + (size_t)b * bstride + l0;
  if (t < 128) {
    int r = t >> 4, l = t & 15;
    dl[r][l] = xb[(size_t)r * L + l];
  }
  __syncthreads();
  int d = t;
  float dtwv[8];
#pragma unroll
  for (int r = 0; r < 8; r++) dtwv[r] = dtw[d * 8 + r];
  float dtbv = dtb[d];
  float spv[16];
#pragma unroll
  for (int l = 0; l < 16; l++) {
    float s = dtbv;
#pragma unroll
    for (int r = 0; r < 8; r++) s += dl[r][l] * dtwv[r];
    spv[l] = fmaxf(s, 0.f) + log1pf(expf(-fabsf(s)));
  }
  float* dout = dg + ((size_t)b * 256 + d) * L + l0;
#pragma unroll
  for (int i = 0; i < 4; i++)
    *(float4*)&dout[4 * i] = make_float4(spv[4 * i], spv[4 * i + 1],
                                         spv[4 * i + 2], spv[4 * i + 3]);
}

// ---------------------------------------------------------------------------
// Segment-parallel selective scan, pass A. SEG=64: lvl1 bid = sid*16+tseg
// (4096); lvl2 4096 + sid*4+tseg (1024). B read directly from xd rows 8..23.
// ---------------------------------------------------------------------------
#define SCAN_STEPA(DVV, DXV, BVV) {                     \
    float e_ = __builtin_amdgcn_exp2f((DVV) * A2);      \
    h = h * e_ + (BVV) * (DXV);                         \
    S += (DVV); }

__global__ __launch_bounds__(256) void scanA_k(
    const unsigned short* __restrict__ f1b, const unsigned short* __restrict__ f2b,
    const float* __restrict__ d1f, const float* __restrict__ d1b,
    const float* __restrict__ d2,
    const float* __restrict__ xd12, const float* __restrict__ xd2,
    const float* __restrict__ Al1, const float* __restrict__ Al2,
    float* __restrict__ cP, float* __restrict__ cQ)
{
  __shared__ __align__(16) float lds[48][68];   // delta[0,16) dx[16,32) B[32,48)
  int bid = blockIdx.x;
  int sid, tseg, L; const unsigned short* xin;
  if (bid < 4096) { sid = bid >> 4; tseg = bid & 15; L = 1024; xin = f1b; }
  else { int idx = bid - 4096; sid = idx >> 2; tseg = idx & 3; L = 256; xin = f2b; }
  int b = sid >> 5, dir = (sid >> 4) & 1, g = sid & 15;
  const float *dlp, *Alp, *xdp;
  if (bid < 4096) {
    xdp = xd12 + ((size_t)b * 80 + dir * 40) * 1024;
    if (dir == 0) { dlp = d1f; Alp = Al1; }
    else          { dlp = d1b; Alp = Al2; }
  } else {
    xdp = xd2 + (size_t)b * 40 * 256;
    dlp = d2; Alp = Al2;
  }
  int t = threadIdx.x, n = t & 15, dloc = t >> 4, d = g * 16 + dloc;
  int mbase = dir ? (L - 64 * (tseg + 1)) : 64 * tseg;

  int r0 = t >> 4, cs = t & 15;
  {
    const float* p0 = dlp + ((size_t)b * 256 + g * 16 + r0) * L + mbase;
    const unsigned short* p1 = xin + ((size_t)b * 256 + g * 16 + r0) * L + mbase;
    const float* p2 = xdp + (size_t)(8 + r0) * L + mbase;
    float4 v0 = *(const float4*)(p0 + cs * 4);
    float4 xf = bf2f4(*(const ushort4*)(p1 + cs * 4));
    float4 v2 = *(const float4*)(p2 + cs * 4);
    float4 dx = make_float4(v0.x * xf.x, v0.y * xf.y, v0.z * xf.z, v0.w * xf.w);
    *(float4*)&lds[r0][cs * 4]      = v0;
    *(float4*)&lds[16 + r0][cs * 4] = dx;
    *(float4*)&lds[32 + r0][cs * 4] = v2;
  }
  __syncthreads();

  float A2 = -expf(Alp[d * 16 + n]) * 1.442695040888963f;
  float h = 0.f, S = 0.f;
  if (dir == 0) {
#pragma unroll
    for (int g4 = 0; g4 < 16; g4++) {
      int cb = 4 * g4;
      float4 dv4 = *(const float4*)&lds[dloc][cb];
      float4 dx4 = *(const float4*)&lds[16 + dloc][cb];
      float4 bv4 = *(const float4*)&lds[32 + n][cb];
      SCAN_STEPA(dv4.x, dx4.x, bv4.x);
      SCAN_STEPA(dv4.y, dx4.y, bv4.y);
      SCAN_STEPA(dv4.z, dx4.z, bv4.z);
      SCAN_STEPA(dv4.w, dx4.w, bv4.w);
    }
  } else {
#pragma unroll
    for (int g4 = 0; g4 < 16; g4++) {
      int cb = 60 - 4 * g4;
      float4 dv4 = *(const float4*)&lds[dloc][cb];
      float4 dx4 = *(const float4*)&lds[16 + dloc][cb];
      float4 bv4 = *(const float4*)&lds[32 + n][cb];
      SCAN_STEPA(dv4.w, dx4.w, bv4.w);
      SCAN_STEPA(dv4.z, dx4.z, bv4.z);
      SCAN_STEPA(dv4.y, dx4.y, bv4.y);
      SCAN_STEPA(dv4.x, dx4.x, bv4.x);
    }
  }
  cP[(size_t)bid * 256 + t] = __builtin_amdgcn_exp2f(S * A2);
  cQ[(size_t)bid * 256 + t] = h;
}

// ---------------------------------------------------------------------------
// scanB_k: per-chain serial combine of per-segment carries into EXCLUSIVE
// prefix initial states. Grid: 256 (lvl1, S=16) + 256 (lvl2, S=4) = 512.
// ---------------------------------------------------------------------------
__global__ __launch_bounds__(256) void scanB_k(
    const float* __restrict__ cP, const float* __restrict__ cQ,
    float* __restrict__ cH)
{
  int bid = blockIdx.x, t = threadIdx.x;
  if (bid < 256) {
    size_t base = (size_t)bid * 16 * 256 + t;
    float h = 0.f;
#pragma unroll
    for (int s = 0; s < 16; ++s) {
      size_t off = base + (size_t)s * 256;
      cH[off] = h;
      h = cP[off] * h + cQ[off];
    }
  } else {
    size_t base = (size_t)(4096 + (bid - 256) * 4) * 256 + t;
    float h = 0.f;
#pragma unroll
    for (int s = 0; s < 4; ++s) {
      size_t off = base + (size_t)s * 256;
      cH[off] = h;
      h = cP[off] * h + cQ[off];
    }
  }
}

// ---------------------------------------------------------------------------
// scanC (quad-n, SEG=64): lane owns 4 n-states of one d; block = 64 d x one
// 64-step segment. Initial h = ONE float4 from cH. delta read from global
// (quad-uniform, L2-warm); B/C staged transposed from xd rows 8..23/24..39.
// LDS = x(bf16) + B + C = 19.4KB. Grid: 1024 + 256 + 64 = 1344.
// ---------------------------------------------------------------------------
#define QSTEP(DS, XU, CI, II) {                                         \
    float4 bv = *(const float4*)&ld_b[CI][n0];                          \
    float4 cv = *(const float4*)&ld_c[CI][n0];                          \
    float xs_ = bf2f(XU) * (DS);                                        \
    float4 e_;                                                          \
    e_.x = __builtin_amdgcn_exp2f((DS) * A4.x);                         \
    e_.y = __builtin_amdgcn_exp2f((DS) * A4.y);                         \
    e_.z = __builtin_amdgcn_exp2f((DS) * A4.z);                         \
    e_.w = __builtin_amdgcn_exp2f((DS) * A4.w);                         \
    h4.x = h4.x * e_.x + bv.x * xs_;                                    \
    h4.y = h4.y * e_.y + bv.y * xs_;                                    \
    h4.z = h4.z * e_.z + bv.z * xs_;                                    \
    h4.w = h4.w * e_.w + bv.w * xs_;                                    \
    float pp_ = h4.x * cv.x + h4.y * cv.y + h4.z * cv.z + h4.w * cv.w;  \
    pp_ = qadd<0xB1>(pp_);                                              \
    pp_ = qadd<0x4E>(pp_);                                              \
    ysel = (nq == (II)) ? pp_ : ysel; }

__global__ __launch_bounds__(256) void scanC_k(
    const unsigned short* __restrict__ f1b, const unsigned short* __restrict__ f2b,
    const unsigned short* __restrict__ f3b,
    const float* __restrict__ d1f, const float* __restrict__ d1b,
    const float* __restrict__ d2,  const float* __restrict__ d3,
    const float* __restrict__ xd12, const float* __restrict__ xd2,
    const float* __restrict__ xd3,
    float* __restrict__ y1f, float* __restrict__ y1b,
    float* __restrict__ y2f, float* __restrict__ y2b,
    float* __restrict__ y3f, float* __restrict__ y3b,
    const float* __restrict__ Al1, const float* __restrict__ Dv1,
    const float* __restrict__ Al2, const float* __restrict__ Dv2,
    const float* __restrict__ Al3, const float* __restrict__ Dv3,
    const float* __restrict__ cH)
{
  __shared__ __align__(16) unsigned short ld_xs[64][72]; // x bf16
  __shared__ __align__(16) float ld_b[64][20];           // B transposed [t][n]
  __shared__ __align__(16) float ld_c[64][20];           // C transposed [t][n]

  int bid = blockIdx.x;
  int b, dir, g4, tseg, L, lvl;
  const unsigned short* xin; const float *dlp, *xdp, *Alp, *Dvp; float* yo;
  if (bid < 1024) {
    b = bid >> 7; dir = (bid >> 6) & 1; g4 = (bid >> 4) & 3; tseg = bid & 15;
    L = 1024; xin = f1b; lvl = 1;
    xdp = xd12 + ((size_t)b * 80 + dir * 40) * 1024;
    if (dir == 0) { dlp = d1f; Alp = Al1; Dvp = Dv1; yo = y1f; }
    else          { dlp = d1b; Alp = Al2; Dvp = Dv2; yo = y1b; }
  } else if (bid < 1280) {
    int idx = bid - 1024;
    b = idx >> 5; dir = (idx >> 4) & 1; g4 = (idx >> 2) & 3; tseg = idx & 3;
    L = 256; xin = f2b; lvl = 2;
    xdp = xd2 + (size_t)b * 40 * 256;
    dlp = d2; Alp = Al2; Dvp = Dv2; yo = dir ? y2b : y2f;
  } else {
    int idx = bid - 1280;
    b = idx >> 3; dir = (idx >> 2) & 1; g4 = idx & 3; tseg = 0;
    L = 64; xin = f3b; lvl = 3;
    xdp = xd3 + (size_t)b * 40 * 64;
    dlp = d3; Alp = Al3; Dvp = Dv3; yo = dir ? y3b : y3f;
  }
  int mbase = dir ? (L - 64 * (tseg + 1)) : 64 * tseg;
  int t = threadIdx.x;
  int dl = t >> 2, nq = t & 3, n0 = nq * 4;
  int d = g4 * 64 + dl;

  // ---- initial h: one float4 from scanB's exclusive-prefix table ----
  float4 h4 = make_float4(0.f, 0.f, 0.f, 0.f);
  if (lvl != 3) {
    int gold = g4 * 4 + (dl >> 4);
    int soff = (lvl == 1) ? (b * 32 + dir * 16 + gold) * 16
                          : 4096 + (b * 32 + dir * 16 + gold) * 4;
    h4 = *(const float4*)&cH[(size_t)(soff + tseg) * 256 +
                             (size_t)((dl & 15) * 16 + n0)];
  }

  // ---- staging: x bf16 (rows = d), B/C transposed to [t][n] ----
  {
    int rr = t >> 2, q = t & 3;
    const unsigned short* xr = xin + ((size_t)b * 256 + g4 * 64 + rr) * L + mbase;
#pragma unroll
    for (int j = 0; j < 4; ++j) {
      int c = q * 4 + 16 * j;
      *(ushort4*)&ld_xs[rr][c] = *(const ushort4*)(xr + c);
    }
    int nn = t >> 4, c4 = t & 15;
    const float* br = xdp + (size_t)(8 + nn) * L + mbase + c4 * 4;
    const float* cr = xdp + (size_t)(24 + nn) * L + mbase + c4 * 4;
    float4 bv = *(const float4*)br;
    float4 cv = *(const float4*)cr;
    ld_b[c4 * 4 + 0][nn] = bv.x; ld_b[c4 * 4 + 1][nn] = bv.y;
    ld_b[c4 * 4 + 2][nn] = bv.z; ld_b[c4 * 4 + 3][nn] = bv.w;
    ld_c[c4 * 4 + 0][nn] = cv.x; ld_c[c4 * 4 + 1][nn] = cv.y;
    ld_c[c4 * 4 + 2][nn] = cv.z; ld_c[c4 * 4 + 3][nn] = cv.w;
  }

  // delta row for this thread's d (quad-uniform address -> one line per quad)
  const float* drow = dlp + ((size_t)b * 256 + d) * L + mbase;

  // A prescaled by log2(e) so e = exp2(delta * A4)
  float4 A4;
  A4.x = -expf(Alp[d * 16 + n0 + 0]) * 1.442695040888963f;
  A4.y = -expf(Alp[d * 16 + n0 + 1]) * 1.442695040888963f;
  A4.z = -expf(Alp[d * 16 + n0 + 2]) * 1.442695040888963f;
  A4.w = -expf(Alp[d * 16 + n0 + 3]) * 1.442695040888963f;
  float Dvv = Dvp[d];
  __syncthreads();

  float* ybase = yo + ((size_t)b * L + mbase) * 256 + d;
  if (dir == 0) {
#pragma unroll 1
    for (int p = 0; p < 4; ++p) {
      float yk[4];
#pragma unroll
      for (int j = 0; j < 4; ++j) {
        int cb = 16 * p + 4 * j;
        float4 dv4 = *(const float4*)(drow + cb);
        ushort4 xu4 = *(const ushort4*)&ld_xs[dl][cb];
        float ysel = 0.f;
        QSTEP(dv4.x, xu4.x, cb + 0, 0);
        QSTEP(dv4.y, xu4.y, cb + 1, 1);
        QSTEP(dv4.z, xu4.z, cb + 2, 2);
        QSTEP(dv4.w, xu4.w, cb + 3, 3);
        yk[j] = ysel;
      }
#pragma unroll
      for (int j = 0; j < 4; ++j) {
        int cst = 16 * p + 4 * j + nq;
        float xv = bf2f(ld_xs[dl][cst]);
        ybase[(size_t)cst * 256] = yk[j] + xv * Dvv;
      }
    }
  } else {
#pragma unroll 1
    for (int p = 0; p < 4; ++p) {
      float yk[4];
#pragma unroll
      for (int j = 0; j < 4; ++j) {
        int cb = 60 - 16 * p - 4 * j;
        float4 dv4 = *(const float4*)(drow + cb);
        ushort4 xu4 = *(const ushort4*)&ld_xs[dl][cb];
        float ysel = 0.f;
        QSTEP(dv4.w, xu4.w, cb + 3, 0);
        QSTEP(dv4.z, xu4.z, cb + 2, 1);
        QSTEP(dv4.y, xu4.y, cb + 1, 2);
        QSTEP(dv4.x, xu4.x, cb + 0, 3);
        yk[j] = ysel;
      }
#pragma unroll
      for (int j = 0; j < 4; ++j) {
        int cst = 60 - 16 * p - 4 * j + (3 - nq);
        float xv = bf2f(ld_xs[dl][cst]);
        ybase[(size_t)cst * 256] = yk[j] + xv * Dvv;
      }
    }
  }
}

// ---------------------------------------------------------------------------
// LayerNorm(fwd)+LayerNorm(bwd) + optional upsample add + optional *silu(z).
// Wave-per-row: 4 rows/block, lane owns 4 channels, 6 shfl_xor reduce.
// ---------------------------------------------------------------------------
template <int OUTBF>
__global__ __launch_bounds__(256) void ln_combine(
    const float* __restrict__ yf, const float* __restrict__ yb,
    const float* __restrict__ gf, const float* __restrict__ bef,
    const float* __restrict__ gb, const float* __restrict__ beb,
    const float* __restrict__ up, int Wc,
    const unsigned short* __restrict__ szb, void* __restrict__ outv,
    int L, int Lsh, int Wfsh)
{
  int t = threadIdx.x;
  int row = blockIdx.x * 4 + (t >> 6);
  int lane = t & 63;
  int b = row >> Lsh, l = row & (L - 1);
  size_t base = (size_t)row * 256 + lane * 4;
  float4 vf = *(const float4*)&yf[base];
  float4 vb = *(const float4*)&yb[base];
  float4 s;
  s.x = vf.x + vf.y + vf.z + vf.w;
  s.y = vf.x * vf.x + vf.y * vf.y + vf.z * vf.z + vf.w * vf.w;
  s.z = vb.x + vb.y + vb.z + vb.w;
  s.w = vb.x * vb.x + vb.y * vb.y + vb.z * vb.z + vb.w * vb.w;
#pragma unroll
  for (int m = 1; m < 64; m <<= 1) {
    s.x += __shfl_xor(s.x, m);
    s.y += __shfl_xor(s.y, m);
    s.z += __shfl_xor(s.z, m);
    s.w += __shfl_xor(s.w, m);
  }
  const float inv = 1.f / 256.f;
  float muf = s.x * inv, varf = s.y * inv - muf * muf;
  float mub = s.z * inv, varb = s.w * inv - mub * mub;
  float rf = rsqrtf(varf + 1e-5f);
  float rb = rsqrtf(varb + 1e-5f);
  int dc = lane * 4;
  float4 gfv = *(const float4*)&gf[dc];
  float4 befv = *(const float4*)&bef[dc];
  float4 gbv = *(const float4*)&gb[dc];
  float4 bebv = *(const float4*)&beb[dc];
  float4 v;
  v.x = (vf.x - muf) * rf * gfv.x + befv.x + (vb.x - mub) * rb * gbv.x + bebv.x;
  v.y = (vf.y - muf) * rf * gfv.y + befv.y + (vb.y - mub) * rb * gbv.y + bebv.y;
  v.z = (vf.z - muf) * rf * gfv.z + befv.z + (vb.z - mub) * rb * gbv.z + bebv.z;
  v.w = (vf.w - muf) * rf * gfv.w + befv.w + (vb.w - mub) * rb * gbv.w + bebv.w;
  if (up) {
    int y = l >> Wfsh, x = l & ((1 << Wfsh) - 1);
    int lc = (y >> 1) * Wc + (x >> 1);
    float4 uv = *(const float4*)&up[((size_t)b * (L >> 2) + lc) * 256 + dc];
    v.x += uv.x; v.y += uv.y; v.z += uv.z; v.w += uv.w;
  }
  if (szb) {
    ushort4 su = *(const ushort4*)&szb[base];
    v.x *= bf2f(su.x); v.y *= bf2f(su.y); v.z *= bf2f(su.z); v.w *= bf2f(su.w);
  }
  if (OUTBF) {
    ushort4 o;
    o.x = f2bf(v.x); o.y = f2bf(v.y); o.z = f2bf(v.z); o.w = f2bf(v.w);
    *(ushort4*)&((unsigned short*)outv)[base] = o;
  } else {
    *(float4*)&((float*)outv)[base] = v;
  }
}

// ---------------------------------------------------------------------------
extern "C" void kernel_launch(void* const* d_in, const int* in_sizes, int n_in,
                              void* d_out, int out_size, void* d_ws, size_t ws_size,
                              hipStream_t stream) {
  (void)in_sizes; (void)n_in; (void)out_size; (void)ws_size;
  const float* input_f = (const float*)d_in[0];
  const float* in_w  = (const float*)d_in[1];
  const float* in_b  = (const float*)d_in[2];
  const float* c1_w  = (const float*)d_in[3];
  const float* c1_b  = (const float*)d_in[4];
  const float* c2_w  = (const float*)d_in[5];
  const float* c2_b  = (const float*)d_in[6];
  const float* c3_w  = (const float*)d_in[7];
  const float* c3_b  = (const float*)d_in[8];
  const float* out_w = (const float*)d_in[9];
  const float* out_b = (const float*)d_in[10];
  const float* xw1  = (const float*)d_in[11];
  const float* dtw1 = (const float*)d_in[12];
  const float* dtb1 = (const float*)d_in[13];
  const float* Al1  = (const float*)d_in[14];
  const float* Dv1  = (const float*)d_in[15];
  const float* g1   = (const float*)d_in[16];
  const float* be1  = (const float*)d_in[17];
  const float* xw2  = (const float*)d_in[18];
  const float* dtw2 = (const float*)d_in[19];
  const float* dtb2 = (const float*)d_in[20];
  const float* Al2  = (const float*)d_in[21];
  const float* Dv2  = (const float*)d_in[22];
  const float* g2   = (const float*)d_in[23];
  const float* be2  = (const float*)d_in[24];
  const float* xw3  = (const float*)d_in[25];
  const float* dtw3 = (const float*)d_in[26];
  const float* dtb3 = (const float*)d_in[27];
  const float* Al3  = (const float*)d_in[28];
  const float* Dv3  = (const float*)d_in[29];
  const float* g3   = (const float*)d_in[30];
  const float* be3  = (const float*)d_in[31];

  float* ws = (float*)d_ws;
  constexpr size_t M1 = 2097152;   // 8*256*1024 floats = 8 MB
  // Region map; lifetimes verified against launch order:
  float* d1f = ws;                                      // R0 fp32 8MB
  unsigned short* f1t = (unsigned short*)(ws + M1);     // R1 [0,4MB) dead after fat1
  float* y1f = ws + M1;                                 // R1 (after f1t dead)
  unsigned short* szb = (unsigned short*)(ws + 2 * M1); // R2 [0,4MB) alive->ln1
  unsigned short* f1b = (unsigned short*)(ws + 3 * M1); // R3 [0,4MB) alive->scanC
  unsigned short* G = (unsigned short*)(ws + 3 * M1) + 2097152; // R3 [4,8MB)
  float* d1b = ws + 4 * M1;                             // R4 fp32 8MB
  unsigned short* inT = (unsigned short*)(ws + 5 * M1); // R5 [0,8MB) dead after ip2
  unsigned short* ic2 = inT;                            // R5 [0,4MB)
  unsigned short* ic3 = inT + 2097152;                  // R5 [4,8MB)
  float* y1b = ws + 5 * M1;                             // R5 (after ic2/ic3 dead)
  size_t o = 6 * M1;
  unsigned short* f2b = (unsigned short*)(ws + o); o += 524288;  // 1MB used
  unsigned short* f3b = (unsigned short*)(ws + o); o += 131072;
  float* d2   = ws + o; o += 524288;
  float* d3   = ws + o; o += 131072;
  float* y2f  = ws + o; o += 524288;
  float* y2b  = ws + o; o += 524288;
  float* y3f  = ws + o; o += 131072;
  float* y3b  = ws + o; o += 131072;
  float* y3c  = ws + o; o += 131072;
  float* y2c  = ws + o; o += 524288;
  float* cP   = ws + o; o += 1310720;   // 5120 blocks x 256
  float* cQ   = ws + o; o += 1310720;
  float* cH   = ws + o; o += 1310720;   // scanB exclusive-prefix states
  float* xd12 = ws + o; o += 655360;    // (b,80,1024) alive -> scanC
  float* xd2  = ws + o; o += 81920;     // (b,40,256)
  float* xd3  = ws + o; o += 20480;     // (b,40,64)
  unsigned short* wsW = (unsigned short*)(ws + o); o += 506880;
  float* bias_fz = ws + o; o += 512;
  unsigned short* w_fz = (unsigned short*)(ws + o); o += 131072;  // 512x512 bf16
  // pixel-major bf16 f2/f3 alias cQ (dead before scanA writes cQ):
  unsigned short* f2t = (unsigned short*)cQ;            // (b,256,256)
  unsigned short* f3t = (unsigned short*)(cQ + 262144); // (b,64,256)
  // bf16 weight sub-pointers:
  unsigned short* w_c2   = wsW + 327680;   // k-reordered
  unsigned short* w_c3   = wsW + 589824;   // k-reordered
  unsigned short* w_out  = wsW + 851968;
  unsigned short* w_xw12 = wsW + 983040;   // [xw1;xw2] stacked (80x256)
  unsigned short* w_xw2  = wsW + 993280;
  unsigned short* w_xw3  = wsW + 1003520;

  dim3 blk(256);

  // 1. weights->bf16 + input transpose + W1/bias compose (fused)
  prep_k<<<dim3(8448), blk, 0, stream>>>(in_w, c1_w, c2_w, c3_w, out_w,
                                         xw1, xw2, xw3, wsW, input_f, inT,
                                         in_b, c1_b, w_fz, bias_fz);
  // 2. fused in-proj+c1: f1t + f1b + szb in one GEMM
  mgemm_k<1><<<dim3(256), blk, 0, stream>>>(inT, 1024 * 512, w_fz, 0, bias_fz,
                                            f1t, f1b, szb, 1024, 512, 512, 8, 4);
  // 3. fat1: xd12 GEMM + im2col2 (both read f1t only)
  fat1_k<<<dim3(1088), blk, 0, stream>>>(w_xw12, f1t, xd12, ic2);
  // 4. c2 small-tile (dual bf16): f2b + f2t  (256 blocks)
  cgemm_k<<<dim3(256), blk, 0, stream>>>(w_c2, ic2, 256 * 1024, c2_b,
                                         f2b, f2t, 256, 256, 1024, 4, 8);
  // 5. fat2: xd2 GEMM + im2col3 (both read f2t only)
  fat2_k<<<dim3(272), blk, 0, stream>>>(w_xw2, f2t, xd2, ic3);
  // 6. c3 small-tile (dual bf16): f3b + f3t  (64 blocks)
  cgemm_k<<<dim3(64), blk, 0, stream>>>(w_c3, ic3, 64 * 1024, c3_b,
                                        f3b, f3t, 256, 64, 1024, 4, 2);
  // 7. xd3
  mgemm_k<0><<<dim3(8), blk, 0, stream>>>(w_xw3, 0, f3t, 64 * 256, nullptr,
                                          xd3, nullptr, nullptr, 40, 64, 256, 1, 1);
  // 8. delta/softplus only (bc copy deleted; scans read B/C from xd)
  post_all_k<<<dim3(1184), blk, 0, stream>>>(xd12, xd2, xd3,
                                             dtw1, dtb1, dtw2, dtb2, dtw3, dtb3,
                                             d1f, d1b, d2, d3);
  // 9-11. segment-parallel scan, SEG=64: per-seg carries, prefix combine, apply
  scanA_k<<<dim3(5120), blk, 0, stream>>>(f1b, f2b, d1f, d1b, d2,
                                          xd12, xd2, Al1, Al2, cP, cQ);
  scanB_k<<<dim3(512), blk, 0, stream>>>(cP, cQ, cH);
  scanC_k<<<dim3(1344), blk, 0, stream>>>(f1b, f2b, f3b,
                                          d1f, d1b, d2, d3, xd12, xd2, xd3,
                                          y1f, y1b, y2f, y2b, y3f, y3b,
                                          Al1, Dv1, Al2, Dv2, Al3, Dv3, cH);
  // 12-14. LN + combine, wave-per-row (level 1 multiplies silu(z), writes bf16 G)
  ln_combine<0><<<dim3(128), blk, 0, stream>>>(y3f, y3b, g3, be3, g3, be3,
                                               nullptr, 0, nullptr, y3c, 64, 6, 3);
  ln_combine<0><<<dim3(512), blk, 0, stream>>>(y2f, y2b, g2, be2, g2, be2,
                                               y3c, 8, nullptr, y2c, 256, 8, 4);
  ln_combine<1><<<dim3(2048), blk, 0, stream>>>(y1f, y1b, g1, be1, g2, be2,
                                                y2c, 16, szb, G, 1024, 10, 5);
  // 15. out-proj -> d_out fp32 (b,512,1024)
  mgemm_k<0><<<dim3(256), blk, 0, stream>>>(w_out, 0, G, 1024 * 256, out_b,
                                            (float*)d_out, nullptr, nullptr,
                                            512, 1024, 256, 4, 8);
}